// Round 1
// 492.342 us; speedup vs baseline: 1.1768x; 1.1768x over previous
//
#include <hip/hip_runtime.h>

typedef _Float16 f16;
typedef _Float16 f16x8 __attribute__((ext_vector_type(8)));
typedef _Float16 f16x4 __attribute__((ext_vector_type(4)));
typedef float f32x4 __attribute__((ext_vector_type(4)));

#define MFMA16(a, b, c) __builtin_amdgcn_mfma_f32_16x16x32_f16((a), (b), (c), 0, 0, 0)
#define CLAMP01(x) __builtin_amdgcn_fmed3f((x), 0.0f, 1.0f)

constexpr int BATCH = 16384;
constexpr int H     = 256;
constexpr int IN    = 784;
constexpr int OUT   = 10;
constexpr int TSTEP = 50;
constexpr int BM    = 16;    // batch rows per block
constexpr int NTHR  = 512;   // 8 waves; role-split: waves 0-3 update s2, 4-7 update s1
constexpr int SROW  = 264;   // padded f16 row stride (33 x 16B quads -> conflict-free b128)
constexpr int S0ROW = 40;    // padded f16 row stride for s0 tile (K padded 10->32)
constexpr int DROW  = 808;   // data staging stride: 101 quads (odd) -> conflict-free prologue reads
constexpr int XROW  = 268;   // f32 stride of x2 hand-off buffer (268 mod 32 = 12 -> <=2-way)

// LDS pool offsets (f16 units). Data staging [16][808]=12928 f16 overlays the
// state buffers (not live during the x2 prologue). The x2 f32 hand-off buffer
// [16][268] f32 = 17152 B also overlays the state buffers (consumed before the
// initial state writeback). Epilogue f32 transpose buffer overlays them too.
constexpr int OFF_S1_0 = 0;
constexpr int OFF_S1_1 = BM * SROW;            // 4224
constexpr int OFF_S2_0 = 2 * BM * SROW;        // 8448
constexpr int OFF_S2_1 = 3 * BM * SROW;        // 12672
constexpr int OFF_S0_0 = 4 * BM * SROW;        // 16896
constexpr int OFF_S0_1 = OFF_S0_0 + BM * S0ROW;
constexpr int OFF_W0N  = OFF_S0_1 + BM * S0ROW; // 18176
constexpr int POOL_F16 = OFF_W0N + 16 * SROW;   // 22400 f16 = 44800 B

// NOTE: second arg MUST stay 2. With 2 waves/EU the unified VGPR+AGPR budget is
// 256/wave. Role-split worst path: w[4][8]=128 + o[4]+sm[4]+bh[4]=48 + wave0
// (oz,s0m,b0h)=12 + w0c[4]/b0v=20 + addressing ~ 230-250. (NTHR,4) would cap at
// 128 -> weights spill to scratch -> multi-GB HBM traffic, 3x slower (measured R2).
__global__ __launch_bounds__(NTHR, 2) void ep_step_kernel(
    const float* __restrict__ data, const float* __restrict__ s0_in,
    const float* __restrict__ s1_in, const float* __restrict__ s2_in,
    const float* __restrict__ W0, const float* __restrict__ b0,
    const float* __restrict__ W2, const float* __restrict__ b2,
    const float* __restrict__ W4, const float* __restrict__ b4,
    float* __restrict__ out)
{
    __shared__ __align__(16) f16 pool[POOL_F16];

    const int tid  = threadIdx.x;
    const int wave = tid >> 6;
    const int lane = tid & 63;
    const int q    = lane >> 4;   // quad 0..3
    const int l16  = lane & 15;
    const int m0   = blockIdx.x * BM;
    const bool isS1 = (wave >= 4);      // waves 4-7: update s1 (read s2,s0); 0-3: update s2 (read s1)
    const int h0   = (wave & 3) * 64;   // 64-row h slab this wave owns in the main loop (4 tiles of 16)
    const int hx   = wave * 32;         // 32-row h slab for the x2 prologue (all 8 waves share the work)

    // ---- phase 1: stage rho(data)->f16 LDS (overlay), W0-natural tile, zero s0 bufs ----------
    for (int i = tid; i < BM * (DROW / 4); i += NTHR) {
        int m  = i / (DROW / 4);
        int k4 = (i % (DROW / 4)) * 4;
        f16x4 p = {(f16)0.f, (f16)0.f, (f16)0.f, (f16)0.f};
        if (k4 < IN) {
            f32x4 v = *(const f32x4*)(data + (size_t)(m0 + m) * IN + k4);
            #pragma unroll
            for (int j = 0; j < 4; ++j) p[j] = (f16)CLAMP01(v[j]);
        }
        *(f16x4*)&pool[m * DROW + k4] = p;
    }
    for (int i = tid; i < 16 * SROW; i += NTHR) {
        int o = i / SROW, k = i % SROW;
        pool[OFF_W0N + i] = (o < OUT && k < H) ? (f16)W0[o * H + k] : (f16)0.f;
    }
    for (int i = tid; i < 2 * BM * S0ROW; i += NTHR) pool[OFF_S0_0 + i] = (f16)0.f;
    __syncthreads();

    // ---- phase 2a: x2 = rho(data) @ W4^T (transposed C[h][m]) — all 8 waves, 32h each --------
    f32x4 x2a[2] = {{0.f, 0.f, 0.f, 0.f}, {0.f, 0.f, 0.f, 0.f}};
    for (int kk = 0; kk < 25; ++kk) {
        int kb = kk * 32 + q * 8;
        f16x8 bd = *(const f16x8*)&pool[l16 * DROW + kb];
        #pragma unroll
        for (int ht = 0; ht < 2; ++ht) {
            int h = hx + ht * 16 + l16;
            f16x8 wa4;
            if (kk < 24) {
                f32x4 u0 = *(const f32x4*)(W4 + (size_t)h * IN + kb);
                f32x4 u1 = *(const f32x4*)(W4 + (size_t)h * IN + kb + 4);
                #pragma unroll
                for (int j = 0; j < 4; ++j) { wa4[j] = (f16)u0[j]; wa4[j + 4] = (f16)u1[j]; }
            } else {
                #pragma unroll
                for (int j = 0; j < 8; ++j) {
                    int k = kb + j;
                    wa4[j] = (k < IN) ? (f16)W4[(size_t)h * IN + k] : (f16)0.f;
                }
            }
            x2a[ht] = MFMA16(wa4, bd, x2a[ht]);
        }
    }
    __syncthreads();  // data staging overlay dead beyond this point

    // ---- phase 2b: hand x2 slabs (32h per producer) to their owning s2-updater (64h) ---------
    float* xf0 = (float*)pool;  // [16][XROW] f32 overlay
    #pragma unroll
    for (int ht = 0; ht < 2; ++ht)
        *(f32x4*)&xf0[l16 * XROW + hx + ht * 16 + q * 4] = x2a[ht];
    __syncthreads();

    // ---- phase 3: persistent role-specific weight fragments (ONE W2 orientation per wave) ----
    f16x8 w[4][8];
    f16x8 w0c[4];   // s1-updaters only: A'[h][o] = W0[o][h], K padded 10->32
    if (!isS1) {
        // s2-update: o2 = s1 @ W2  ->  A'[h][k] = W2[k][h]
        #pragma unroll
        for (int ht = 0; ht < 4; ++ht) {
            int h = h0 + ht * 16 + l16;
            #pragma unroll
            for (int kk = 0; kk < 8; ++kk) {
                int kb = kk * 32 + q * 8;
                f16x8 wa;
                #pragma unroll
                for (int j = 0; j < 8; ++j) wa[j] = (f16)W2[(kb + j) * H + h];
                w[ht][kk] = wa;
            }
        }
    } else {
        // s1-update: o1 = s2 @ W2^T  ->  A'[h][k] = W2[h][k]
        #pragma unroll
        for (int ht = 0; ht < 4; ++ht) {
            int h = h0 + ht * 16 + l16;
            #pragma unroll
            for (int kk = 0; kk < 8; ++kk) {
                int kb = kk * 32 + q * 8;
                f32x4 u0 = *(const f32x4*)(W2 + h * H + kb);
                f32x4 u1 = *(const f32x4*)(W2 + h * H + kb + 4);
                f16x8 wb;
                #pragma unroll
                for (int j = 0; j < 4; ++j) { wb[j] = (f16)u0[j]; wb[j + 4] = (f16)u1[j]; }
                w[ht][kk] = wb;
            }
            #pragma unroll
            for (int j = 0; j < 8; ++j) {
                int o = q * 8 + j;
                w0c[ht][j] = (o < OUT) ? (f16)W0[o * H + h] : (f16)0.f;
            }
        }
    }

    // ---- pre-halved biases + fp32 master state (C layout: row h = q*4+r, col m = l16) --------
    f32x4 bh[4], sm[4];
    const float* sin_p = isS1 ? s1_in : s2_in;
    #pragma unroll
    for (int ht = 0; ht < 4; ++ht)
        #pragma unroll
        for (int r = 0; r < 4; ++r) {
            int h = h0 + ht * 16 + q * 4 + r;
            bh[ht][r] = isS1 ? 0.5f * b2[h]
                             : 0.5f * (xf0[l16 * XROW + h] + b4[h]);
            sm[ht][r] = sin_p[(size_t)(m0 + l16) * H + h];
        }
    f32x4 s0m = {0.f, 0.f, 0.f, 0.f}, b0h = {0.f, 0.f, 0.f, 0.f};
    if (wave == 0) {
        #pragma unroll
        for (int r = 0; r < 4; ++r) {
            int o = q * 4 + r;
            if (o < OUT) { s0m[r] = s0_in[(size_t)(m0 + l16) * OUT + o]; b0h[r] = 0.5f * b0[o]; }
        }
    }
    __syncthreads();  // xf0 consumed; state buffers may now be written

    f16* const s1b[2] = {&pool[OFF_S1_0], &pool[OFF_S1_1]};
    f16* const s2b[2] = {&pool[OFF_S2_0], &pool[OFF_S2_1]};
    f16* const s0b[2] = {&pool[OFF_S0_0], &pool[OFF_S0_1]};

    // conflict-free b64 writeback: 4 consecutive h per lane at stride 33 quads.
    // Each wave writes only the ONE state it owns (4 tiles of 16h).
    auto writeback = [&](f16* ws1, f16* ws2, f16* ws0) {
        f16* ws = isS1 ? ws1 : ws2;
        #pragma unroll
        for (int ht = 0; ht < 4; ++ht) {
            int hb = h0 + ht * 16 + q * 4;
            f16x4 p;
            #pragma unroll
            for (int r = 0; r < 4; ++r) p[r] = (f16)sm[ht][r];
            *(f16x4*)&ws[l16 * SROW + hb] = p;
        }
        if (wave == 0) {
            int ob = q * 4;
            if (ob < OUT) {  // q = 0,1,2 ; o=10,11 padded with zeros
                f16x4 p;
                #pragma unroll
                for (int r = 0; r < 4; ++r) p[r] = (ob + r < OUT) ? (f16)s0m[r] : (f16)0.f;
                *(f16x4*)&ws0[l16 * S0ROW + ob] = p;
            }
        }
    };

    auto do_step = [&](const f16* rs1, const f16* rs2, const f16* rs0,
                       f16* ws1, f16* ws2, f16* ws0) {
        const f16* rsrc = isS1 ? rs2 : rs1;   // read the OPPOSITE state, full K
        f16x8 b0v;
        if (isS1) b0v = *(const f16x8*)&rs0[l16 * S0ROW + q * 8];
        f32x4 o[4] = {{0.f,0.f,0.f,0.f},{0.f,0.f,0.f,0.f},{0.f,0.f,0.f,0.f},{0.f,0.f,0.f,0.f}};
        f32x4 oz   = {0.f, 0.f, 0.f, 0.f};
        #pragma unroll
        for (int kk = 0; kk < 8; ++kk) {
            f16x8 b = *(const f16x8*)&rsrc[l16 * SROW + kk * 32 + q * 8];
            o[0] = MFMA16(w[0][kk], b, o[0]);
            o[1] = MFMA16(w[1][kk], b, o[1]);
            o[2] = MFMA16(w[2][kk], b, o[2]);
            o[3] = MFMA16(w[3][kk], b, o[3]);
            if (wave == 0) {  // s0-update rides on wave 0's full-s1 reads
                f16x8 a0 = *(const f16x8*)&pool[OFF_W0N + l16 * SROW + kk * 32 + q * 8];
                oz = MFMA16(a0, b, oz);
            }
        }
        if (isS1) {  // + rho(s0) @ W0 term
            o[0] = MFMA16(w0c[0], b0v, o[0]);
            o[1] = MFMA16(w0c[1], b0v, o[1]);
            o[2] = MFMA16(w0c[2], b0v, o[2]);
            o[3] = MFMA16(w0c[3], b0v, o[3]);
        }
        #pragma unroll
        for (int ht = 0; ht < 4; ++ht)
            #pragma unroll
            for (int r = 0; r < 4; ++r)
                sm[ht][r] = CLAMP01(fmaf(0.5f, sm[ht][r], fmaf(0.5f, o[ht][r], bh[ht][r])));
        if (wave == 0) {
            #pragma unroll
            for (int r = 0; r < 4; ++r)
                s0m[r] = CLAMP01(fmaf(0.5f, s0m[r], fmaf(0.5f, oz[r], b0h[r])));
        }
        writeback(ws1, ws2, ws0);
    };

    writeback(s1b[0], s2b[0], s0b[0]);
    __syncthreads();

    // ---- main loop: one barrier per step via double buffering --------------------------------
    #pragma unroll 1
    for (int t = 0; t < TSTEP; t += 2) {
        do_step(s1b[0], s2b[0], s0b[0], s1b[1], s2b[1], s0b[1]);
        __syncthreads();
        do_step(s1b[1], s2b[1], s0b[1], s1b[0], s2b[0], s0b[0]);
        __syncthreads();
    }

    // ---- epilogue: coalesced output via LDS transpose (overlay on state buffers) --------------
    if (wave == 0) {
        #pragma unroll
        for (int r = 0; r < 4; ++r) {
            int o = q * 4 + r;
            if (o < OUT) out[(size_t)(m0 + l16) * OUT + o] = s0m[r];
        }
    }
    float* xf = (float*)pool;  // [16][264] f32
    float* o1p = out + (size_t)BATCH * OUT;
    float* o2p = o1p + (size_t)BATCH * H;
    if (isS1) {
        #pragma unroll
        for (int ht = 0; ht < 4; ++ht)
            *(f32x4*)&xf[l16 * 264 + h0 + ht * 16 + q * 4] = sm[ht];
    }
    __syncthreads();
    for (int i = tid; i < BM * H / 4; i += NTHR) {
        int m = i >> 6, c = (i & 63) * 4;
        f32x4 v = *(const f32x4*)&xf[m * 264 + c];
        *(f32x4*)&o1p[(size_t)(m0 + m) * H + c] = v;
    }
    __syncthreads();
    if (!isS1) {
        #pragma unroll
        for (int ht = 0; ht < 4; ++ht)
            *(f32x4*)&xf[l16 * 264 + h0 + ht * 16 + q * 4] = sm[ht];
    }
    __syncthreads();
    for (int i = tid; i < BM * H / 4; i += NTHR) {
        int m = i >> 6, c = (i & 63) * 4;
        f32x4 v = *(const f32x4*)&xf[m * 264 + c];
        *(f32x4*)&o2p[(size_t)(m0 + m) * H + c] = v;
    }
}

extern "C" void kernel_launch(void* const* d_in, const int* in_sizes, int n_in,
                              void* d_out, int out_size, void* d_ws, size_t ws_size,
                              hipStream_t stream) {
    const float* data  = (const float*)d_in[0];
    const float* s0_in = (const float*)d_in[1];
    const float* s1_in = (const float*)d_in[2];
    const float* s2_in = (const float*)d_in[3];
    const float* W0    = (const float*)d_in[4];
    const float* b0    = (const float*)d_in[5];
    const float* W2    = (const float*)d_in[6];
    const float* b2    = (const float*)d_in[7];
    const float* W4    = (const float*)d_in[8];
    const float* b4    = (const float*)d_in[9];
    float* out = (float*)d_out;

    ep_step_kernel<<<BATCH / BM, NTHR, 0, stream>>>(
        data, s0_in, s1_in, s2_in, W0, b0, W2, b2, W4, b4, out);
}

// Round 2
// 431.245 us; speedup vs baseline: 1.3435x; 1.1417x over previous
//
#include <hip/hip_runtime.h>

typedef _Float16 f16;
typedef _Float16 f16x8 __attribute__((ext_vector_type(8)));
typedef _Float16 f16x4 __attribute__((ext_vector_type(4)));
typedef float f32x4 __attribute__((ext_vector_type(4)));

#define MFMA16(a, b, c) __builtin_amdgcn_mfma_f32_16x16x32_f16((a), (b), (c), 0, 0, 0)
#define CLAMP01(x) __builtin_amdgcn_fmed3f((x), 0.0f, 1.0f)

constexpr int BATCH = 16384;
constexpr int H     = 256;
constexpr int IN    = 784;
constexpr int OUT   = 10;
constexpr int TSTEP = 50;
constexpr int BM    = 32;    // batch rows per block: 2 column-tiles of 16 -> grid 512, 2 rounds
constexpr int NTHR  = 512;   // 8 waves; role-split: waves 0-3 update s2, 4-7 update s1
constexpr int SROW  = 264;   // padded f16 row stride (33 x 16B quads -> conflict-free b128)
constexpr int S0ROW = 40;    // padded f16 row stride for s0 tile (K padded 10->32)
constexpr int DROW  = 808;   // data staging stride (odd quad count -> conflict-free)
constexpr int XROW  = 268;   // f32 stride of x2 hand-off buffer (<=2-3 way on b128)

// LDS pool (f16 units). Overlays (all barrier-separated):
//   data staging [32][808] = 25856 f16 over the state buffers (pre-loop only)
//   x2 hand-off  [32][268] f32 = 17152 f16 over the state buffers (pre-loop only)
//   epilogue     [32][264] f32 = 16896 f16 over the state buffers (post-loop only)
constexpr int OFF_S1_0 = 0;
constexpr int OFF_S1_1 = BM * SROW;             // 8448
constexpr int OFF_S2_0 = 2 * BM * SROW;         // 16896
constexpr int OFF_S2_1 = 3 * BM * SROW;         // 25344
constexpr int OFF_S0_0 = 4 * BM * SROW;         // 33792
constexpr int OFF_S0_1 = OFF_S0_0 + BM * S0ROW; // 35072
constexpr int OFF_W0N  = OFF_S0_1 + BM * S0ROW; // 36352
constexpr int POOL_F16 = OFF_W0N + 16 * SROW;   // 40576 f16 = 81152 B -> 1 block/CU

// Register budget (unified VGPR+AGPR, 2 waves/EU -> 256/wave):
//   s2 wave: w 128 + sm(in-place acc) 32 + bx 32 + temps ~20 = ~212
//   s1 wave: w 128 + w0c 16 + sm 32 + bh 16 + temps ~20 = ~212
// The in-place accumulate (acc0 = s + b_full, s' = clamp(0.5*acc)) removes the
// separate o[] accumulator array that would otherwise push past 256.
__global__ __launch_bounds__(NTHR, 2) void ep_step_kernel(
    const float* __restrict__ data, const float* __restrict__ s0_in,
    const float* __restrict__ s1_in, const float* __restrict__ s2_in,
    const float* __restrict__ W0, const float* __restrict__ b0,
    const float* __restrict__ W2, const float* __restrict__ b2,
    const float* __restrict__ W4, const float* __restrict__ b4,
    float* __restrict__ out)
{
    __shared__ __align__(16) f16 pool[POOL_F16];

    const int tid  = threadIdx.x;
    const int wave = tid >> 6;
    const int lane = tid & 63;
    const int q    = lane >> 4;   // quad 0..3
    const int l16  = lane & 15;
    const int m0   = blockIdx.x * BM;
    const bool isS1 = (wave >= 4);     // waves 4-7: update s1 (read s2,s0); 0-3: update s2 (read s1)
    const bool duty = (wave < 2);      // s0-update rides on waves 0,1 (they read full s1)
    const int  dmt  = wave & 1;        // duty wave's m-tile
    const int h0   = (wave & 3) * 64;  // 64-row h slab in the main loop (4 tiles of 16)
    const int hx   = wave * 32;        // 32-row h slab for the x2 prologue

    // ---- phase 1: stage rho(data)->f16 LDS (overlay), W0-natural tile, zero s0 bufs ----------
    for (int i = tid; i < BM * (DROW / 4); i += NTHR) {
        int m  = i / (DROW / 4);
        int k4 = (i % (DROW / 4)) * 4;
        f16x4 p = {(f16)0.f, (f16)0.f, (f16)0.f, (f16)0.f};
        if (k4 < IN) {
            f32x4 v = *(const f32x4*)(data + (size_t)(m0 + m) * IN + k4);
            #pragma unroll
            for (int j = 0; j < 4; ++j) p[j] = (f16)CLAMP01(v[j]);
        }
        *(f16x4*)&pool[m * DROW + k4] = p;
    }
    for (int i = tid; i < 16 * SROW; i += NTHR) {
        int o = i / SROW, k = i % SROW;
        pool[OFF_W0N + i] = (o < OUT && k < H) ? (f16)W0[o * H + k] : (f16)0.f;
    }
    for (int i = tid; i < 2 * BM * S0ROW; i += NTHR) pool[OFF_S0_0 + i] = (f16)0.f;
    __syncthreads();

    // ---- phase 2a: x2 = rho(data) @ W4^T (C[h][m]) — all 8 waves, 32h x 32m each -------------
    f32x4 x2a[2][2] = {{{0.f,0.f,0.f,0.f},{0.f,0.f,0.f,0.f}},
                       {{0.f,0.f,0.f,0.f},{0.f,0.f,0.f,0.f}}};
    for (int kk = 0; kk < 25; ++kk) {
        int kb = kk * 32 + q * 8;
        f16x8 bd0 = *(const f16x8*)&pool[l16 * DROW + kb];
        f16x8 bd1 = *(const f16x8*)&pool[(16 + l16) * DROW + kb];
        #pragma unroll
        for (int ht = 0; ht < 2; ++ht) {
            int h = hx + ht * 16 + l16;
            f16x8 wa4;
            if (kk < 24) {
                f32x4 u0 = *(const f32x4*)(W4 + (size_t)h * IN + kb);
                f32x4 u1 = *(const f32x4*)(W4 + (size_t)h * IN + kb + 4);
                #pragma unroll
                for (int j = 0; j < 4; ++j) { wa4[j] = (f16)u0[j]; wa4[j + 4] = (f16)u1[j]; }
            } else {
                #pragma unroll
                for (int j = 0; j < 8; ++j) {
                    int k = kb + j;
                    wa4[j] = (k < IN) ? (f16)W4[(size_t)h * IN + k] : (f16)0.f;
                }
            }
            x2a[ht][0] = MFMA16(wa4, bd0, x2a[ht][0]);
            x2a[ht][1] = MFMA16(wa4, bd1, x2a[ht][1]);
        }
    }
    __syncthreads();  // data staging overlay dead beyond this point

    // ---- phase 2b: hand (x2 + b4) slabs to their owning s2-updater ---------------------------
    float* xf0 = (float*)pool;  // [32][XROW] f32 overlay
    #pragma unroll
    for (int ht = 0; ht < 2; ++ht) {
        f32x4 v0 = x2a[ht][0], v1 = x2a[ht][1];
        #pragma unroll
        for (int r = 0; r < 4; ++r) {
            float bb = b4[hx + ht * 16 + q * 4 + r];
            v0[r] += bb; v1[r] += bb;
        }
        *(f32x4*)&xf0[l16 * XROW + hx + ht * 16 + q * 4]        = v0;
        *(f32x4*)&xf0[(16 + l16) * XROW + hx + ht * 16 + q * 4] = v1;
    }
    __syncthreads();

    // ---- phase 3: persistent role-specific weight fragments + full biases --------------------
    f16x8 w[4][8];
    f16x8 w0c[4];    // s1-updaters: A'[h][o] = W0[o][h], K padded 10->32
    f32x4 bx[4][2];  // s2-updaters: full bias  b = x2 + b4  (per h AND m)
    f32x4 bh[4];     // s1-updaters: full bias  b = b2       (per h)
    if (!isS1) {
        // s2-update: o2 = s1 @ W2  ->  A'[h][k] = W2[k][h]
        #pragma unroll
        for (int ht = 0; ht < 4; ++ht) {
            int h = h0 + ht * 16 + l16;
            #pragma unroll
            for (int kk = 0; kk < 8; ++kk) {
                int kb = kk * 32 + q * 8;
                f16x8 wa;
                #pragma unroll
                for (int j = 0; j < 8; ++j) wa[j] = (f16)W2[(kb + j) * H + h];
                w[ht][kk] = wa;
            }
            bx[ht][0] = *(const f32x4*)&xf0[l16 * XROW + h0 + ht * 16 + q * 4];
            bx[ht][1] = *(const f32x4*)&xf0[(16 + l16) * XROW + h0 + ht * 16 + q * 4];
        }
    } else {
        // s1-update: o1 = s2 @ W2^T  ->  A'[h][k] = W2[h][k]
        #pragma unroll
        for (int ht = 0; ht < 4; ++ht) {
            int h = h0 + ht * 16 + l16;
            #pragma unroll
            for (int kk = 0; kk < 8; ++kk) {
                int kb = kk * 32 + q * 8;
                f32x4 u0 = *(const f32x4*)(W2 + h * H + kb);
                f32x4 u1 = *(const f32x4*)(W2 + h * H + kb + 4);
                f16x8 wb;
                #pragma unroll
                for (int j = 0; j < 4; ++j) { wb[j] = (f16)u0[j]; wb[j + 4] = (f16)u1[j]; }
                w[ht][kk] = wb;
            }
            #pragma unroll
            for (int j = 0; j < 8; ++j) {
                int o = q * 8 + j;
                w0c[ht][j] = (o < OUT) ? (f16)W0[o * H + h] : (f16)0.f;
            }
            bh[ht] = *(const f32x4*)&b2[h0 + ht * 16 + q * 4];
        }
    }

    // fp32 master state, C layout (row h = q*4+r, col m = mt*16+l16); in-place MFMA accumulator
    f32x4 sm[4][2];
    const float* sin_p = isS1 ? s1_in : s2_in;
    #pragma unroll
    for (int ht = 0; ht < 4; ++ht)
        #pragma unroll
        for (int mt = 0; mt < 2; ++mt)
            sm[ht][mt] = *(const f32x4*)&sin_p[(size_t)(m0 + mt * 16 + l16) * H + h0 + ht * 16 + q * 4];
    f32x4 s0m = {0.f, 0.f, 0.f, 0.f}, b0f = {0.f, 0.f, 0.f, 0.f};
    if (duty) {
        #pragma unroll
        for (int r = 0; r < 4; ++r) {
            int o = q * 4 + r;
            if (o < OUT) {
                s0m[r] = s0_in[(size_t)(m0 + dmt * 16 + l16) * OUT + o];
                b0f[r] = b0[o];
            }
        }
    }
    __syncthreads();  // xf0 consumed; state buffers may now be written

    f16* const s1b[2] = {&pool[OFF_S1_0], &pool[OFF_S1_1]};
    f16* const s2b[2] = {&pool[OFF_S2_0], &pool[OFF_S2_1]};
    f16* const s0b[2] = {&pool[OFF_S0_0], &pool[OFF_S0_1]};

    // conflict-free b64 writeback: 4 consecutive h per lane at stride 33 quads
    auto writeback = [&](f16* ws1, f16* ws2, f16* ws0) {
        f16* ws = isS1 ? ws1 : ws2;
        #pragma unroll
        for (int ht = 0; ht < 4; ++ht) {
            int hb = h0 + ht * 16 + q * 4;
            #pragma unroll
            for (int mt = 0; mt < 2; ++mt) {
                f16x4 p;
                #pragma unroll
                for (int r = 0; r < 4; ++r) p[r] = (f16)sm[ht][mt][r];
                *(f16x4*)&ws[(mt * 16 + l16) * SROW + hb] = p;
            }
        }
        if (duty) {
            int ob = q * 4;
            if (ob < OUT) {  // q = 0,1,2 ; o=10,11 padded with zeros
                f16x4 p;
                #pragma unroll
                for (int r = 0; r < 4; ++r) p[r] = (ob + r < OUT) ? (f16)s0m[r] : (f16)0.f;
                *(f16x4*)&ws0[(dmt * 16 + l16) * S0ROW + ob] = p;
            }
        }
    };

    auto do_step = [&](const f16* rs1, const f16* rs2, const f16* rs0,
                       f16* ws1, f16* ws2, f16* ws0) {
        const f16* rsrc = isS1 ? rs2 : rs1;   // read the OPPOSITE state, full K
        // fold previous state + full bias into the accumulator: acc0 = s + b
        if (isS1) {
            #pragma unroll
            for (int ht = 0; ht < 4; ++ht) { sm[ht][0] += bh[ht]; sm[ht][1] += bh[ht]; }
        } else {
            #pragma unroll
            for (int ht = 0; ht < 4; ++ht) { sm[ht][0] += bx[ht][0]; sm[ht][1] += bx[ht][1]; }
        }
        f16x8 b0v0, b0v1;
        if (isS1) {
            b0v0 = *(const f16x8*)&rs0[l16 * S0ROW + q * 8];
            b0v1 = *(const f16x8*)&rs0[(16 + l16) * S0ROW + q * 8];
        }
        if (duty) s0m += b0f;
        #pragma unroll
        for (int kk = 0; kk < 8; ++kk) {
            int kb = kk * 32 + q * 8;
            f16x8 bA = *(const f16x8*)&rsrc[l16 * SROW + kb];
            f16x8 bB = *(const f16x8*)&rsrc[(16 + l16) * SROW + kb];
            sm[0][0] = MFMA16(w[0][kk], bA, sm[0][0]); sm[0][1] = MFMA16(w[0][kk], bB, sm[0][1]);
            sm[1][0] = MFMA16(w[1][kk], bA, sm[1][0]); sm[1][1] = MFMA16(w[1][kk], bB, sm[1][1]);
            sm[2][0] = MFMA16(w[2][kk], bA, sm[2][0]); sm[2][1] = MFMA16(w[2][kk], bB, sm[2][1]);
            sm[3][0] = MFMA16(w[3][kk], bA, sm[3][0]); sm[3][1] = MFMA16(w[3][kk], bB, sm[3][1]);
            if (duty) {  // s0-update rides on the duty wave's own s1 fragments
                f16x8 a0 = *(const f16x8*)&pool[OFF_W0N + l16 * SROW + kb];
                s0m = MFMA16(a0, dmt == 0 ? bA : bB, s0m);
            }
        }
        if (isS1) {  // + rho(s0) @ W0 term
            #pragma unroll
            for (int ht = 0; ht < 4; ++ht) {
                sm[ht][0] = MFMA16(w0c[ht], b0v0, sm[ht][0]);
                sm[ht][1] = MFMA16(w0c[ht], b0v1, sm[ht][1]);
            }
        }
        #pragma unroll
        for (int ht = 0; ht < 4; ++ht)
            #pragma unroll
            for (int mt = 0; mt < 2; ++mt)
                #pragma unroll
                for (int r = 0; r < 4; ++r)
                    sm[ht][mt][r] = CLAMP01(0.5f * sm[ht][mt][r]);
        if (duty) {
            #pragma unroll
            for (int r = 0; r < 4; ++r) s0m[r] = CLAMP01(0.5f * s0m[r]);
        }
        writeback(ws1, ws2, ws0);
    };

    writeback(s1b[0], s2b[0], s0b[0]);
    __syncthreads();

    // ---- main loop: one barrier per step via double buffering --------------------------------
    #pragma unroll 1
    for (int t = 0; t < TSTEP; t += 2) {
        do_step(s1b[0], s2b[0], s0b[0], s1b[1], s2b[1], s0b[1]);
        __syncthreads();
        do_step(s1b[1], s2b[1], s0b[1], s1b[0], s2b[0], s0b[0]);
        __syncthreads();
    }

    // ---- epilogue: coalesced output via LDS transpose (overlay on state buffers) --------------
    if (duty) {
        #pragma unroll
        for (int r = 0; r < 4; ++r) {
            int o = q * 4 + r;
            if (o < OUT) out[(size_t)(m0 + dmt * 16 + l16) * OUT + o] = s0m[r];
        }
    }
    float* xf = (float*)pool;  // [32][264] f32
    float* o1p = out + (size_t)BATCH * OUT;
    float* o2p = o1p + (size_t)BATCH * H;
    if (isS1) {
        #pragma unroll
        for (int ht = 0; ht < 4; ++ht)
            #pragma unroll
            for (int mt = 0; mt < 2; ++mt)
                *(f32x4*)&xf[(mt * 16 + l16) * 264 + h0 + ht * 16 + q * 4] = sm[ht][mt];
    }
    __syncthreads();
    for (int i = tid; i < BM * H / 4; i += NTHR) {
        int m = i >> 6, c = (i & 63) * 4;
        f32x4 v = *(const f32x4*)&xf[m * 264 + c];
        *(f32x4*)&o1p[(size_t)(m0 + m) * H + c] = v;
    }
    __syncthreads();
    if (!isS1) {
        #pragma unroll
        for (int ht = 0; ht < 4; ++ht)
            #pragma unroll
            for (int mt = 0; mt < 2; ++mt)
                *(f32x4*)&xf[(mt * 16 + l16) * 264 + h0 + ht * 16 + q * 4] = sm[ht][mt];
    }
    __syncthreads();
    for (int i = tid; i < BM * H / 4; i += NTHR) {
        int m = i >> 6, c = (i & 63) * 4;
        f32x4 v = *(const f32x4*)&xf[m * 264 + c];
        *(f32x4*)&o2p[(size_t)(m0 + m) * H + c] = v;
    }
}

extern "C" void kernel_launch(void* const* d_in, const int* in_sizes, int n_in,
                              void* d_out, int out_size, void* d_ws, size_t ws_size,
                              hipStream_t stream) {
    const float* data  = (const float*)d_in[0];
    const float* s0_in = (const float*)d_in[1];
    const float* s1_in = (const float*)d_in[2];
    const float* s2_in = (const float*)d_in[3];
    const float* W0    = (const float*)d_in[4];
    const float* b0    = (const float*)d_in[5];
    const float* W2    = (const float*)d_in[6];
    const float* b2    = (const float*)d_in[7];
    const float* W4    = (const float*)d_in[8];
    const float* b4    = (const float*)d_in[9];
    float* out = (float*)d_out;

    ep_step_kernel<<<BATCH / BM, NTHR, 0, stream>>>(
        data, s0_in, s1_in, s2_in, W0, b0, W2, b2, W4, b4, out);
}

// Round 3
// 383.102 us; speedup vs baseline: 1.5123x; 1.1257x over previous
//
#include <hip/hip_runtime.h>

typedef _Float16 f16;
typedef _Float16 f16x8 __attribute__((ext_vector_type(8)));
typedef _Float16 f16x4 __attribute__((ext_vector_type(4)));
typedef float f32x4 __attribute__((ext_vector_type(4)));

#define MFMA16(a, b, c) __builtin_amdgcn_mfma_f32_16x16x32_f16((a), (b), (c), 0, 0, 0)
#define CLAMP01(x) __builtin_amdgcn_fmed3f((x), 0.0f, 1.0f)

constexpr int BATCH = 16384;
constexpr int H     = 256;
constexpr int IN    = 784;
constexpr int OUT   = 10;
constexpr int TSTEP = 50;
constexpr int BM    = 64;    // 4 m-tiles of 16 -> grid 256 = 1 block/CU, ONE round
constexpr int NTHR  = 512;   // 8 waves; waves 0-3 update s2 (read s1), 4-7 update s1 (read s2,s0)
constexpr int SROW  = 264;   // f16 row stride: 2-way max on b128 (free per m136)
constexpr int S0ROW = 40;    // f16 stride, s0 tile, K padded 10->32
constexpr int DROW  = 808;   // f16 stride, data staging overlay
constexpr int BXROW = 268;   // f32 stride, x2-bias buffer: 268%32=12 -> 2-way max
constexpr int W0TROW= 16;    // f16 stride, W0^T tile (only o<16 stored; q>=2 lanes use zeros)
constexpr int EROW  = 268;   // f32 stride, epilogue transpose buffer

// LDS map (f16 units), total 158,976 B <= 160 KiB -> 1 block/CU (required anyway).
// Overlays, all barrier-separated: data staging [64][808]=103,424 B from offset 0
// (pre-loop); epilogue f32 [64][268]=68,608 B from offset 0 (post-loop).
constexpr int OFF_S1  = 0;
constexpr int OFF_S2  = OFF_S1 + BM * SROW;      // 16896
constexpr int OFF_S0  = OFF_S2 + BM * SROW;      // 33792
constexpr int OFF_W0N = OFF_S0 + BM * S0ROW;     // 36352
constexpr int OFF_W0T = OFF_W0N + 16 * SROW;     // 40576
constexpr int OFF_B2  = OFF_W0T + H * W0TROW;    // 44672 : f32[256] (pre-halved b2)
constexpr int OFF_BX  = OFF_B2 + 2 * H;          // 45184 : f32[64][268] (pre-halved x2+b4, [m][h])
constexpr int POOL_F16 = OFF_BX + 2 * BM * BXROW; // 79488 f16 = 158,976 B

// Register budget (unified VGPR+AGPR 256/wave at 2 waves/EU -- the (NTHR,2) is load-bearing):
//   both roles: w[4][8]=128 VGPR + sm[4][4]=64 AGPR = 192 persistent.
//   s1 extras (b0v+w0c, 32 regs) are consumed BEFORE the kk-loop so they don't
//   overlap the b[4] staging regs; bias is re-read from LDS each step (not held).
__global__ __launch_bounds__(NTHR, 2) void ep_step_kernel(
    const float* __restrict__ data, const float* __restrict__ s0_in,
    const float* __restrict__ s1_in, const float* __restrict__ s2_in,
    const float* __restrict__ W0, const float* __restrict__ b0,
    const float* __restrict__ W2, const float* __restrict__ b2,
    const float* __restrict__ W4, const float* __restrict__ b4,
    float* __restrict__ out)
{
    __shared__ __align__(16) f16 pool[POOL_F16];

    const int tid  = threadIdx.x;
    const int wave = tid >> 6;
    const int lane = tid & 63;
    const int q    = lane >> 4;   // quad 0..3
    const int l16  = lane & 15;
    const int m0   = blockIdx.x * BM;
    const bool isS1 = (wave >= 4);     // role: waves 4-7 update s1; 0-3 update s2
    const int  dmt  = wave & 3;        // s2 waves: m-tile whose s0-update this wave carries
    const int h0   = (wave & 3) * 64;  // 64-row h slab in the main loop (4 tiles of 16)
    const int hx   = wave * 32;        // 32-row h slab for the x2 prologue

    float* const bx  = (float*)&pool[OFF_BX];
    float* const b2l = (float*)&pool[OFF_B2];

    // ---- phase 1: stage rho(data)->f16 into LDS overlay ---------------------------------------
    for (int i = tid; i < BM * (DROW / 4); i += NTHR) {
        int m  = i / (DROW / 4);
        int k4 = (i % (DROW / 4)) * 4;
        f16x4 p = {(f16)0.f, (f16)0.f, (f16)0.f, (f16)0.f};
        if (k4 < IN) {
            f32x4 v = *(const f32x4*)(data + (size_t)(m0 + m) * IN + k4);
            #pragma unroll
            for (int j = 0; j < 4; ++j) p[j] = (f16)CLAMP01(v[j]);
        }
        *(f16x4*)&pool[m * DROW + k4] = p;
    }
    __syncthreads();

    // ---- phase 2: x2 = rho(data) @ W4^T (C[h][m]) -- all 8 waves, 32h x 64m each --------------
    f32x4 x2a[2][4] = {};
    for (int kk = 0; kk < 25; ++kk) {
        int kb = kk * 32 + q * 8;
        f16x8 bd[4];
        #pragma unroll
        for (int mt = 0; mt < 4; ++mt)
            bd[mt] = *(const f16x8*)&pool[(mt * 16 + l16) * DROW + kb];
        #pragma unroll
        for (int ht = 0; ht < 2; ++ht) {
            int h = hx + ht * 16 + l16;
            f16x8 wa4;
            if (kk < 24) {
                f32x4 u0 = *(const f32x4*)(W4 + (size_t)h * IN + kb);
                f32x4 u1 = *(const f32x4*)(W4 + (size_t)h * IN + kb + 4);
                #pragma unroll
                for (int j = 0; j < 4; ++j) { wa4[j] = (f16)u0[j]; wa4[j + 4] = (f16)u1[j]; }
            } else {
                #pragma unroll
                for (int j = 0; j < 8; ++j) {
                    int k = kb + j;
                    wa4[j] = (k < IN) ? (f16)W4[(size_t)h * IN + k] : (f16)0.f;
                }
            }
            #pragma unroll
            for (int mt = 0; mt < 4; ++mt)
                x2a[ht][mt] = MFMA16(wa4, bd[mt], x2a[ht][mt]);
        }
    }
    __syncthreads();  // staging overlay dead

    // ---- phase 3: persistent small LDS tiles (all overlap the dead staging region) ------------
    // bias buffer, TRANSPOSED [m][h], pre-halved: 0.5*(x2+b4)
    #pragma unroll
    for (int ht = 0; ht < 2; ++ht)
        #pragma unroll
        for (int mt = 0; mt < 4; ++mt) {
            f32x4 v = x2a[ht][mt];
            #pragma unroll
            for (int r = 0; r < 4; ++r) v[r] = 0.5f * (v[r] + b4[hx + ht * 16 + q * 4 + r]);
            *(f32x4*)&bx[(mt * 16 + l16) * BXROW + hx + ht * 16 + q * 4] = v;
        }
    for (int i = tid; i < 16 * SROW; i += NTHR) {
        int o = i / SROW, k = i % SROW;
        pool[OFF_W0N + i] = (o < OUT && k < H) ? (f16)W0[o * H + k] : (f16)0.f;
    }
    for (int i = tid; i < H * W0TROW; i += NTHR) {
        int h = i / W0TROW, o = i % W0TROW;
        pool[OFF_W0T + i] = (o < OUT) ? (f16)W0[o * H + h] : (f16)0.f;
    }
    for (int i = tid; i < H; i += NTHR) b2l[i] = 0.5f * b2[i];
    for (int i = tid; i < BM * S0ROW; i += NTHR) pool[OFF_S0 + i] = (f16)0.f;
    __syncthreads();

    // ---- phase 4: persistent register weights + fp32 masters ----------------------------------
    asm volatile("" ::: "memory");  // keep the big W2 streams from hoisting into the prologue
    f16x8 w[4][8];
    if (!isS1) {
        // s2-update: o2 = s1 @ W2  ->  A'[h][k] = W2[k][h]
        #pragma unroll
        for (int ht = 0; ht < 4; ++ht) {
            int h = h0 + ht * 16 + l16;
            #pragma unroll
            for (int kk = 0; kk < 8; ++kk) {
                int kb = kk * 32 + q * 8;
                f16x8 wa;
                #pragma unroll
                for (int j = 0; j < 8; ++j) wa[j] = (f16)W2[(kb + j) * H + h];
                w[ht][kk] = wa;
            }
        }
    } else {
        // s1-update: o1 = s2 @ W2^T  ->  A'[h][k] = W2[h][k]
        #pragma unroll
        for (int ht = 0; ht < 4; ++ht) {
            int h = h0 + ht * 16 + l16;
            #pragma unroll
            for (int kk = 0; kk < 8; ++kk) {
                int kb = kk * 32 + q * 8;
                f32x4 u0 = *(const f32x4*)(W2 + h * H + kb);
                f32x4 u1 = *(const f32x4*)(W2 + h * H + kb + 4);
                f16x8 wb;
                #pragma unroll
                for (int j = 0; j < 4; ++j) { wb[j] = (f16)u0[j]; wb[j + 4] = (f16)u1[j]; }
                w[ht][kk] = wb;
            }
        }
    }
    f32x4 sm[4][4];   // master state = in-place MFMA accumulator (C layout: h=q*4+r, m=mt*16+l16)
    const float* sin_p = isS1 ? s1_in : s2_in;
    #pragma unroll
    for (int ht = 0; ht < 4; ++ht)
        #pragma unroll
        for (int mt = 0; mt < 4; ++mt)
            sm[ht][mt] = *(const f32x4*)&sin_p[(size_t)(m0 + mt * 16 + l16) * H + h0 + ht * 16 + q * 4];
    f32x4 s0m = {0.f, 0.f, 0.f, 0.f}, b0h = {0.f, 0.f, 0.f, 0.f};
    if (!isS1) {
        #pragma unroll
        for (int r = 0; r < 4; ++r) {
            int o = q * 4 + r;
            if (o < OUT) {
                s0m[r] = s0_in[(size_t)(m0 + dmt * 16 + l16) * OUT + o];
                b0h[r] = 0.5f * b0[o];
            }
        }
    }

    // conflict-free b64 writeback of this wave's OWN state (+ s0 slice for s2 waves)
    auto writeback = [&]() {
        f16* ws = &pool[isS1 ? OFF_S1 : OFF_S2];
        #pragma unroll
        for (int ht = 0; ht < 4; ++ht) {
            int hb = h0 + ht * 16 + q * 4;
            #pragma unroll
            for (int mt = 0; mt < 4; ++mt) {
                f16x4 p;
                #pragma unroll
                for (int r = 0; r < 4; ++r) p[r] = (f16)sm[ht][mt][r];
                *(f16x4*)&ws[(mt * 16 + l16) * SROW + hb] = p;
            }
        }
        if (!isS1) {
            int ob = q * 4;
            if (ob < OUT) {  // q=0,1,2 ; o=10,11 padded with zeros; o>=12 zeroed once in phase 3
                f16x4 p;
                #pragma unroll
                for (int r = 0; r < 4; ++r) p[r] = (ob + r < OUT) ? (f16)s0m[r] : (f16)0.f;
                *(f16x4*)&pool[OFF_S0 + (dmt * 16 + l16) * S0ROW + ob] = p;
            }
        }
    };

    auto compute = [&]() {
        const f16* rs = &pool[isS1 ? OFF_S2 : OFF_S1];  // read the OPPOSITE state, full K
        if (isS1) {
            // s0@W0 term FIRST so its 32 staging regs are dead before the kk-loop
            #pragma unroll
            for (int ht = 0; ht < 4; ++ht) {
                f16x8 w0cv = {};
                if (q < 2)
                    w0cv = *(const f16x8*)&pool[OFF_W0T + (h0 + ht * 16 + l16) * W0TROW + q * 8];
                #pragma unroll
                for (int mt = 0; mt < 4; ++mt) {
                    f16x8 b0v = *(const f16x8*)&pool[OFF_S0 + (mt * 16 + l16) * S0ROW + q * 8];
                    sm[ht][mt] = MFMA16(w0cv, b0v, sm[ht][mt]);
                }
            }
        }
        #pragma unroll
        for (int kk = 0; kk < 8; ++kk) {
            int kb = kk * 32 + q * 8;
            f16x8 b[4];
            #pragma unroll
            for (int mt = 0; mt < 4; ++mt)
                b[mt] = *(const f16x8*)&rs[(mt * 16 + l16) * SROW + kb];
            #pragma unroll
            for (int ht = 0; ht < 4; ++ht)
                #pragma unroll
                for (int mt = 0; mt < 4; ++mt)
                    sm[ht][mt] = MFMA16(w[ht][kk], b[mt], sm[ht][mt]);
            if (!isS1) {
                // s0-update rides on this wave's own m-tile; mt==dmt is wave-uniform (scalar branch)
                f16x8 a0 = *(const f16x8*)&pool[OFF_W0N + l16 * SROW + kb];
                #pragma unroll
                for (int mt = 0; mt < 4; ++mt)
                    if (mt == dmt) s0m = MFMA16(a0, b[mt], s0m);
            }
        }
        // bias (pre-halved, from LDS -- reads issue here, latency hidden behind last MFMAs) + clamp
        if (isS1) {
            #pragma unroll
            for (int ht = 0; ht < 4; ++ht) {
                f32x4 bhv = *(const f32x4*)&b2l[h0 + ht * 16 + q * 4];  // broadcast read
                #pragma unroll
                for (int mt = 0; mt < 4; ++mt)
                    #pragma unroll
                    for (int r = 0; r < 4; ++r)
                        sm[ht][mt][r] = CLAMP01(fmaf(0.5f, sm[ht][mt][r], bhv[r]));
            }
        } else {
            #pragma unroll
            for (int ht = 0; ht < 4; ++ht)
                #pragma unroll
                for (int mt = 0; mt < 4; ++mt) {
                    f32x4 bv = *(const f32x4*)&bx[(mt * 16 + l16) * BXROW + h0 + ht * 16 + q * 4];
                    #pragma unroll
                    for (int r = 0; r < 4; ++r)
                        sm[ht][mt][r] = CLAMP01(fmaf(0.5f, sm[ht][mt][r], bv[r]));
                }
            #pragma unroll
            for (int r = 0; r < 4; ++r)
                s0m[r] = CLAMP01(fmaf(0.5f, s0m[r], b0h[r]));
        }
    };

    writeback();          // initial states into LDS
    __syncthreads();

    // ---- main loop: single-buffered, 2 barriers/step ------------------------------------------
    #pragma unroll 1
    for (int t = 0; t < TSTEP; ++t) {
        compute();        // reads only (opposite state + s0 + bias), accumulates in regs
        __syncthreads();  // all reads of old state done
        writeback();      // write own state in place
        __syncthreads();  // new state visible
    }

    // ---- epilogue: s0 direct; s1/s2 via coalescing LDS transpose (overlay) --------------------
    if (!isS1) {
        #pragma unroll
        for (int r = 0; r < 4; ++r) {
            int o = q * 4 + r;
            if (o < OUT) out[(size_t)(m0 + dmt * 16 + l16) * OUT + o] = s0m[r];
        }
    }
    float* xf = (float*)pool;  // [64][EROW] f32 overlay
    float* o1p = out + (size_t)BATCH * OUT;
    float* o2p = o1p + (size_t)BATCH * H;
    if (isS1) {
        #pragma unroll
        for (int ht = 0; ht < 4; ++ht)
            #pragma unroll
            for (int mt = 0; mt < 4; ++mt)
                *(f32x4*)&xf[(mt * 16 + l16) * EROW + h0 + ht * 16 + q * 4] = sm[ht][mt];
    }
    __syncthreads();
    for (int i = tid; i < BM * H / 4; i += NTHR) {
        int m = i >> 6, c = (i & 63) * 4;
        f32x4 v = *(const f32x4*)&xf[m * EROW + c];
        *(f32x4*)&o1p[(size_t)(m0 + m) * H + c] = v;
    }
    __syncthreads();
    if (!isS1) {
        #pragma unroll
        for (int ht = 0; ht < 4; ++ht)
            #pragma unroll
            for (int mt = 0; mt < 4; ++mt)
                *(f32x4*)&xf[(mt * 16 + l16) * EROW + h0 + ht * 16 + q * 4] = sm[ht][mt];
    }
    __syncthreads();
    for (int i = tid; i < BM * H / 4; i += NTHR) {
        int m = i >> 6, c = (i & 63) * 4;
        f32x4 v = *(const f32x4*)&xf[m * EROW + c];
        *(f32x4*)&o2p[(size_t)(m0 + m) * H + c] = v;
    }
}

extern "C" void kernel_launch(void* const* d_in, const int* in_sizes, int n_in,
                              void* d_out, int out_size, void* d_ws, size_t ws_size,
                              hipStream_t stream) {
    const float* data  = (const float*)d_in[0];
    const float* s0_in = (const float*)d_in[1];
    const float* s1_in = (const float*)d_in[2];
    const float* s2_in = (const float*)d_in[3];
    const float* W0    = (const float*)d_in[4];
    const float* b0    = (const float*)d_in[5];
    const float* W2    = (const float*)d_in[6];
    const float* b2    = (const float*)d_in[7];
    const float* W4    = (const float*)d_in[8];
    const float* b4    = (const float*)d_in[9];
    float* out = (float*)d_out;

    ep_step_kernel<<<BATCH / BM, NTHR, 0, stream>>>(
        data, s0_in, s1_in, s2_in, W0, b0, W2, b2, W4, b4, out);
}